// Round 7
// baseline (552.974 us; speedup 1.0000x reference)
//
#include <hip/hip_runtime.h>

#define N_ 2000
#define L_ 1024

__device__ __forceinline__ float rcpf(float d) { return __builtin_amdgcn_rcpf(d); }
__device__ __forceinline__ float ex2(float x)  { return __builtin_amdgcn_exp2f(x); }

// Division-fused trapezoidal update: for the m,n gates, multiply the update's
// numerator and denominator by dm = eRm-1, merging rcp(dm) and rcp(1+sm) into
// ONE rcp and deleting the urm->sm->qm serial links from the loop-carried chain.
//   m' = (0.00364*um*eRm + (dm-Pm)*m) / (dm+Pm),  Pm = um*(0.00182*eRm+0.00124)
// Singularity (Vn==-35 / Vn==25): substitute patched (numer, denom) constants,
// algebraically identical to the reference's patched rates.
// h,y gates + output sigmoid share one off-chain rcp.
// Trans/step: 3 ex2 (eRm, aH, bH) + 4 rcp (1+G, Dm, Dn, qh*qy*uS).
// Ring-8 z prefetch: step K consumes z[K-1] (slot (K-1)&7), prefetches z[K+7].
#define STEP1(K, RS)                                                          \
  {                                                                           \
    const int kk = (K);                                                       \
    float zc = zb[RS];                                                        \
    int kpre = kk + 7;                                                        \
    int kc = kpre < 1998 ? kpre : 1998;                                       \
    zb[RS] = z[base + kc * L_];                                               \
    /* conductance trees */                                                   \
    float mh   = m * h;                                                       \
    float m2   = m * m;                                                       \
    float valm = m2 * mh;              /* m^3 h */                            \
    float n2   = n * n;                                                       \
    float valn = n2 * n2;              /* n^4  */                             \
    float gy   = __fmaf_rn(y, 0.01f, 0.003f);                                 \
    float G    = __fmaf_rn(valm, 0.4f, __fmaf_rn(valn, 0.35f, gy));           \
    float E    = __fmaf_rn(valm, 2200.0f, __fmaf_rn(valn, -2695.0f, -19.5f)); \
    float rV   = rcpf(1.0f + G);                                              \
    float tVD  = __fmaf_rn(E, 0.02f, __fmaf_rn(2.0f, V, 0.02f));              \
    float Vn   = __fmaf_rn(tVD, rV, -V);     /* (2V+DT(E+1))/(1+G) - V */     \
    /* m,n gates: division-fused update, one ex2 + two parallel rcp */        \
    float eRm  = ex2(__fmaf_rn(Vn, K9, 35.0f * K9));   /* e^{(Vn+35)/9} */    \
    float eRn  = eRm * CN;                             /* e^{(Vn-25)/9} */    \
    float um   = Vn + 35.0f;                                                  \
    float un   = Vn - 25.0f;                                                  \
    float dm   = eRm - 1.0f;                                                  \
    float dn   = eRn - 1.0f;                                                  \
    float Pm   = um * __fmaf_rn(0.00182f, eRm, 0.00124f);                     \
    float Pn   = un * __fmaf_rn(0.0002f,  eRn, 0.00002f);                     \
    float Dm   = dm + Pm;                                                     \
    float Dn   = dn + Pn;                                                     \
    float Nm   = __fmaf_rn(0.00364f * um, eRm, (dm - Pm) * m);                \
    float Nn   = __fmaf_rn(0.0004f  * un, eRn, (dn - Pn) * n);                \
    bool patm  = (Vn == -35.0f);                                              \
    bool patn  = (Vn == 25.0f);                                               \
    Dm = patm ? 1.02798f : Dm;                                                \
    Nm = patm ? __fmaf_rn(0.97202f, m, 0.03276f) : Nm;                        \
    Dn = patn ? 1.0026f  : Dn;                                                \
    Nn = patn ? __fmaf_rn(0.9974f,  n, 0.0036f)  : Nn;                        \
    m = Nm * rcpf(Dm);                                                        \
    n = Nn * rcpf(Dn);                                                        \
    /* h,y gates + sigmoid: off the loop-carried chain, one shared rcp */     \
    float aH   = ex2(__fmaf_rn(Vn, -K12, CAH));   /* 0.25 folded as 2^-2 */   \
    float bH   = ex2(__fmaf_rn(Vn,  K12, CBH));                               \
    float sh   = __fmaf_rn(aH, 0.01f, 0.01f * bH);                            \
    float sy   = __fmaf_rn(zc, 0.01f, 0.001f);                                \
    float qh   = 1.0f + sh;                                                   \
    float qy   = 1.0f + sy;                                                   \
    float numh = __fmaf_rn(aH, 0.02f, __fmaf_rn(-sh, h, h));                  \
    float numy = __fmaf_rn(zc, 0.02f, __fmaf_rn(-sy, y, y));                  \
    float e2   = eRm * eRm;                                                   \
    float ts   = (e2 * eRm) * 0.006737946999085467f;  /* e^{(Vn+20)/3} */     \
    float uS   = 1.0f + ts;                                                   \
    float Pq   = qh * qy;                                                     \
    float Qq   = Pq * uS;                                                     \
    float rc   = rcpf(Qq);                                                    \
    float rhy  = rc * uS;       /* 1/(qh qy) */                               \
    float rS   = rc * Pq;       /* 1/(1+ts)  */                               \
    h = numh * (rhy * qy);                                                    \
    y = numy * (rhy * qh);                                                    \
    V = Vn;                                                                   \
    float sg = ts * rS;                                                       \
    out[base + kk * L_] = sg;                                                 \
  }

__global__ __launch_bounds__(64) void hh_kernel(const float* __restrict__ z,
                                                float* __restrict__ out) {
    const int t   = blockIdx.x * 64 + threadIdx.x;   // chain 0..16383
    const int b   = t >> 10;
    const int l   = t & 1023;
    const int base = b * (N_ * L_) + l;

    const float K9  = 0.16029944898766259f;   // log2(e)/9
    const float K12 = 0.12022458674074695f;   // log2(e)/12
    const float CN  = 0.0012726338013398079f; // e^{-60/9}: eRn = eRm * CN
    const float CAH = -90.0f * K12 - 2.0f;    // aH = exp2(-Vn*K12 + CAH)
    const float CBH =  34.0f * K12 - 2.0f;    // bH = exp2( Vn*K12 + CBH)

    float V = -70.0f;
    float m = 0.0f, n = 0.0f, h = 1.0f, y = 0.0f;

    float zb[8];
#pragma unroll
    for (int i = 0; i < 8; ++i) zb[i] = z[base + i * L_];

    // row 0: sigmoid((-70+20)/3), constant
    out[base] = 5.777750e-8f;

    int k = 1;
    for (int g = 0; g < 249; ++g) {          // K = 1 .. 1992
#pragma unroll
        for (int j = 0; j < 8; ++j) {
            STEP1(k + j, j)
        }
        k += 8;
    }
    // K = 1993 .. 1999 (slots 0..6)
#pragma unroll
    for (int j = 0; j < 7; ++j) {
        STEP1(k + j, j)
    }
}

extern "C" void kernel_launch(void* const* d_in, const int* in_sizes, int n_in,
                              void* d_out, int out_size, void* d_ws, size_t ws_size,
                              hipStream_t stream) {
    const float* z = (const float*)d_in[0];
    float* out = (float*)d_out;
    // 16384 chains x 1 lane = 16384 threads = 256 waves (1 per CU)
    hh_kernel<<<256, 64, 0, stream>>>(z, out);
}

// Round 8
// 478.876 us; speedup vs baseline: 1.1547x; 1.1547x over previous
//
#include <hip/hip_runtime.h>

#define N_ 2000
#define L_ 1024

__device__ __forceinline__ float rcpf(float d) { return __builtin_amdgcn_rcpf(d); }
__device__ __forceinline__ float ex2(float x)  { return __builtin_amdgcn_exp2f(x); }

// Issue-diet step: ~62 VALU slots (lone-wave cadence-bound model).
//  - separate rcp per gate + sigmoid (sharing costs MORE slots at equal trans price)
//  - eRn/aM/aN folded into constants; patches applied to tm=urm*eRm (tm_pat=9 exact)
//  - H exps carry 0.01*0.25 in the exp2 constant (A=0.01*aH, B=0.01*bH)
//  - addressing via wave-uniform row bases (readfirstlane) -> SALU, VGPR voffset=lu
// PRE: 0 = prefetch z[K+7] (no clamp, K+7<=1991), 1 = clamped prefetch, 2 = none.
#define STEP1(K, RS, PRE)                                                     \
  {                                                                           \
    const int kk = (K);                                                       \
    float zc = zb[RS];                                                        \
    if ((PRE) == 0) {                                                         \
      zb[RS] = (zrow + (kk + 7) * L_)[lu];                                    \
    } else if ((PRE) == 1) {                                                  \
      int kc = kk + 7; kc = kc < 1998 ? kc : 1998;                            \
      zb[RS] = (zrow + kc * L_)[lu];                                          \
    }                                                                         \
    /* conductances */                                                        \
    float mh   = m * h;                                                       \
    float m2   = m * m;                                                       \
    float valm = m2 * mh;              /* m^3 h */                            \
    float n2   = n * n;                                                       \
    float valn = n2 * n2;              /* n^4  */                             \
    float gy   = __fmaf_rn(y, 0.01f, 0.003f);                                 \
    float G    = __fmaf_rn(valm, 0.4f, __fmaf_rn(valn, 0.35f, gy));           \
    float E    = __fmaf_rn(valm, 2200.0f, __fmaf_rn(valn, -2695.0f, -19.5f)); \
    float rV   = rcpf(1.0f + G);                                              \
    float tVD  = __fmaf_rn(E, 0.02f, __fmaf_rn(2.0f, V, 0.02f));              \
    float Vn   = __fmaf_rn(tVD, rV, -V);   /* (V(1-G)+.02(E+1))/(1+G) */      \
    /* m,n rates: one ex2; eRn = CN*eRm folded into coefficients */           \
    float eRm  = ex2(__fmaf_rn(Vn, K9, 35.0f * K9));   /* e^{(Vn+35)/9} */    \
    float dm   = eRm - 1.0f;                                                  \
    float dn   = __fmaf_rn(CN, eRm, -1.0f);            /* eRn - 1 */          \
    float um   = Vn + 35.0f;                                                  \
    float un   = Vn - 25.0f;                                                  \
    float rrm  = rcpf(dm);                                                    \
    float rrn  = rcpf(dn);                                                    \
    float urm  = um * rrm;                                                    \
    float urn  = un * rrn;                                                    \
    float sm   = urm * __fmaf_rn(0.00182f, eRm, 0.00124f);                    \
    float sn   = urn * __fmaf_rn(KXN, eRm, 0.00002f);                         \
    float tm   = urm * eRm;                                                   \
    float tn   = urn * eRm;                                                   \
    bool patm  = (Vn == -35.0f);                                              \
    bool patn  = (Vn == 25.0f);                                               \
    sm = patm ? 0.02798f : sm;   tm = patm ? 9.0f   : tm;                     \
    sn = patn ? 0.0026f  : sn;   tn = patn ? TNPAT  : tn;                     \
    /* H (0.01 folded): A=0.01*aH, B=0.01*bH */                               \
    float A    = ex2(__fmaf_rn(Vn, -K12, CAH));                               \
    float Bv   = ex2(__fmaf_rn(Vn,  K12, CBH));                               \
    float sh   = A + Bv;                                                      \
    float sy   = __fmaf_rn(zc, 0.01f, 0.001f);                                \
    /* numerators: coef*t = DT*a-rate */                                      \
    float numm = __fmaf_rn(tm, 0.00364f, __fmaf_rn(-sm, m, m));               \
    float numn = __fmaf_rn(tn, KAN,      __fmaf_rn(-sn, n, n));               \
    float numh = __fmaf_rn(A,  2.0f,     __fmaf_rn(-sh, h, h));               \
    float numy = __fmaf_rn(zc, 0.02f,    __fmaf_rn(-sy, y, y));               \
    m = numm * rcpf(1.0f + sm);                                               \
    n = numn * rcpf(1.0f + sn);                                               \
    h = numh * rcpf(1.0f + sh);                                               \
    y = numy * rcpf(1.0f + sy);                                               \
    V = Vn;                                                                   \
    /* sigmoid((Vn+20)/3): ts = eRm^3 e^-5 */                                 \
    float e2 = eRm * eRm;                                                     \
    float ts = (e2 * eRm) * 0.006737946999085467f;                            \
    float sg = ts * rcpf(1.0f + ts);                                          \
    (orow + kk * L_)[lu] = sg;                                                \
  }

__global__ __launch_bounds__(64) void hh_kernel(const float* __restrict__ z,
                                                float* __restrict__ out) {
    const int t  = blockIdx.x * 64 + threadIdx.x;          // 0 .. 16383
    const int bu = __builtin_amdgcn_readfirstlane(t >> 10); // wave-uniform batch
    const int lu = t & 1023;                                // lane column

    const float* zrow = z   + (size_t)bu * (N_ * L_);
    float*       orow = out + (size_t)bu * (N_ * L_);

    const float K9  = 0.16029944898766259f;    // log2(e)/9
    const float K12 = 0.12022458674074695f;    // log2(e)/12
    const float CN  = 0.0012726338013398079f;  // e^{-60/9}: eRn = CN*eRm
    const float KXN = 2.5452676026796158e-7f;  // 0.0002*CN
    const float KAN = 5.0905352053592316e-7f;  // 0.0004*CN (numn coef)
    const float TNPAT = 7071.948f;             // 0.0036/KAN (patched tn)
    const float CAH = -19.46406899644195f;     // -90*K12 + log2(0.0025)
    const float CBH = -4.556220240589328f;     //  34*K12 + log2(0.0025)

    float V = -70.0f;
    float m = 0.0f, n = 0.0f, h = 1.0f, y = 0.0f;

    float zb[8];
#pragma unroll
    for (int i = 0; i < 8; ++i) zb[i] = (zrow + i * L_)[lu];

    // row 0: sigmoid((-70+20)/3), constant
    orow[lu] = 5.777750e-8f;

    int k = 1;
    for (int g = 0; g < 248; ++g) {            // K = 1 .. 1984, clamp-free
#pragma unroll
        for (int j = 0; j < 8; ++j) {
            STEP1(k + j, j, 0)
        }
        k += 8;
    }
#pragma unroll
    for (int j = 0; j < 8; ++j) {              // K = 1985 .. 1992, clamped
        STEP1(1985 + j, j, 1)
    }
#pragma unroll
    for (int j = 0; j < 7; ++j) {              // K = 1993 .. 1999, no prefetch
        STEP1(1993 + j, j, 2)
    }
}

extern "C" void kernel_launch(void* const* d_in, const int* in_sizes, int n_in,
                              void* d_out, int out_size, void* d_ws, size_t ws_size,
                              hipStream_t stream) {
    const float* z = (const float*)d_in[0];
    float* out = (float*)d_out;
    // 16384 chains x 1 lane = 16384 threads = 256 waves (1 per CU)
    hh_kernel<<<256, 64, 0, stream>>>(z, out);
}